// Round 3
// baseline (302.724 us; speedup 1.0000x reference)
//
#include <hip/hip_runtime.h>
#include <hip/hip_bf16.h>
#include <math.h>

#define BB 128
#define MM 200
#define SS 20
#define DD 128
#define NC 10000
#define CL 10
#define CTILE 16

// Detect index width: queries is [128,20] tokens in [0,100000).
// If int64, words at odd positions are the (zero) high halves.
__global__ void k_detect(const int* __restrict__ q, int* __restrict__ flag) {
    int lane = threadIdx.x;
    int zc = 0;
    for (int i = lane; i < 1024; i += 64) zc += (q[2 * i + 1] == 0);
    for (int off = 32; off; off >>= 1) zc += __shfl_down(zc, off);
    if (lane == 0) *flag = (zc >= 512) ? 1 : 0;  // 1 => int64 indices
}

// Embedding row-sum: one wave per output row, lane handles dims {2l,2l+1}.
// tab is f32 [V][128]; token 0 is padding (contributes zero).
template <int T>
__global__ __launch_bounds__(256) void k_rowsum(const int* __restrict__ idx,
                                                const float* __restrict__ tab,
                                                float* __restrict__ out, int rows,
                                                const int* __restrict__ w64) {
    int row = (blockIdx.x << 2) + (threadIdx.x >> 6);
    if (row >= rows) return;
    int lane = threadIdx.x & 63;
    int shift = *w64;  // 0: int32 words, 1: int64 (read low word, little-endian)
    float ax = 0.f, ay = 0.f;
    for (int s = 0; s < T; ++s) {
        int tok = idx[((size_t)(row * T + s)) << shift];
        if (tok) {
            float2 v = *(const float2*)(tab + (size_t)tok * DD + 2 * lane);
            ax += v.x;
            ay += v.y;
        }
    }
    ((float2*)(out + (size_t)row * DD))[lane] = make_float2(ax, ay);
}

// One hop, one block per batch. 256 threads = 4 waves.
// dotted -> softmax -> o -> u = tanh(u @ Hw^T + o). In-place u update is safe
// (block b reads u[b] into LDS before writing it).
__global__ __launch_bounds__(256) void k_hop(const float* __restrict__ m,
                                             float* __restrict__ u,
                                             const float* __restrict__ Hw,
                                             float* __restrict__ uT) {
    __shared__ float u_s[DD];
    __shared__ float p_s[MM];
    __shared__ float o_s[2][DD];
    __shared__ float red_s;
    int b = blockIdx.x;
    int tid = threadIdx.x;
    int wave = tid >> 6, lane = tid & 63;
    const float* mb = m + (size_t)b * MM * DD;

    if (tid < DD) u_s[tid] = u[b * DD + tid];
    __syncthreads();

    // Phase 1: dotted[mm] = m[b,mm,:] . u   (50 rows per wave, shuffle reduce)
    const float2* u2 = (const float2*)u_s;
    for (int i = 0; i < 50; ++i) {
        int mm = wave * 50 + i;
        float2 v = ((const float2*)(mb + mm * DD))[lane];
        float2 uu = u2[lane];
        float d = v.x * uu.x + v.y * uu.y;
        for (int off = 32; off; off >>= 1) d += __shfl_down(d, off);
        if (lane == 0) p_s[mm] = d;
    }
    __syncthreads();

    // Softmax over 200
    if (wave == 0) {
        float lm = -1e30f;
        for (int i = lane; i < MM; i += 64) lm = fmaxf(lm, p_s[i]);
        for (int off = 32; off; off >>= 1) lm = fmaxf(lm, __shfl_down(lm, off));
        if (lane == 0) red_s = lm;
    }
    __syncthreads();
    float smax = red_s;
    if (tid < MM) p_s[tid] = __expf(p_s[tid] - smax);
    __syncthreads();
    if (wave == 0) {
        float ls = 0.f;
        for (int i = lane; i < MM; i += 64) ls += p_s[i];
        for (int off = 32; off; off >>= 1) ls += __shfl_down(ls, off);
        if (lane == 0) red_s = 1.f / ls;
    }
    __syncthreads();
    float inv = red_s;
    if (tid < MM) p_s[tid] *= inv;
    __syncthreads();

    // Phase 2: o[d] = sum_mm probs[mm] * m[b,mm,d]  (split mm range over 2 halves)
    {
        int d = tid & (DD - 1);
        int h = tid >> 7;
        float acc = 0.f;
        for (int mm = h * 100; mm < h * 100 + 100; ++mm) acc += p_s[mm] * mb[mm * DD + d];
        o_s[h][d] = acc;
    }
    __syncthreads();

    // Phase 3: u[d] = tanh( Hw[d,:] . u + o[d] )
    if (tid < DD) {
        int d = tid;
        const float* hrow = Hw + d * DD;
        float acc = o_s[0][d] + o_s[1][d];
        for (int j = 0; j < DD; ++j) acc += hrow[j] * u_s[j];
        float un = tanhf(acc);
        u[b * DD + d] = un;
        uT[d * BB + b] = un;  // transposed copy for the logits kernel
    }
}

// logits[b, c] = u[b,:] . cand_sum[c,:]; block = 16 candidates x all 128 batches.
// Thread = one batch row; coalesced uT reads; cand tile broadcast from LDS.
// Output is FLOAT32 (reference output dtype) — 64B contiguous per thread.
__global__ __launch_bounds__(128) void k_logits(const float* __restrict__ uT,
                                                const float* __restrict__ cs,
                                                float* __restrict__ out) {
    __shared__ float c_s[CTILE][DD];
    int c0 = blockIdx.x * CTILE;
    int tid = threadIdx.x;  // batch index (also dim index for the tile load)
    for (int j = 0; j < CTILE; ++j) c_s[j][tid] = cs[(size_t)(c0 + j) * DD + tid];
    __syncthreads();
    float acc[CTILE];
#pragma unroll
    for (int j = 0; j < CTILE; ++j) acc[j] = 0.f;
    for (int k = 0; k < DD; ++k) {
        float ub = uT[k * BB + tid];
#pragma unroll
        for (int j = 0; j < CTILE; ++j) acc[j] += ub * c_s[j][k];
    }
    // byte addr = 4*(tid*10000 + 16*blk) = 40000*tid + 64*blk -> 16B aligned
    float4* op = (float4*)(out + (size_t)tid * NC + c0);
    op[0] = make_float4(acc[0], acc[1], acc[2], acc[3]);
    op[1] = make_float4(acc[4], acc[5], acc[6], acc[7]);
    op[2] = make_float4(acc[8], acc[9], acc[10], acc[11]);
    op[3] = make_float4(acc[12], acc[13], acc[14], acc[15]);
}

extern "C" void kernel_launch(void* const* d_in, const int* in_sizes, int n_in,
                              void* d_out, int out_size, void* d_ws, size_t ws_size,
                              hipStream_t stream) {
    const int* stories = (const int*)d_in[0];       // [128,200,20] tokens
    const int* queries = (const int*)d_in[1];       // [128,20]
    const int* cands   = (const int*)d_in[2];       // [10000,10]
    const float* A  = (const float*)d_in[3];        // f32 [100000,128]
    const float* W  = (const float*)d_in[4];        // f32 [100000,128]
    const float* Hw = (const float*)d_in[5];        // f32 [128,128]
    float* out = (float*)d_out;                     // f32 [128,10000]

    float* ws = (float*)d_ws;
    float* m_buf = ws;                          // 128*200*128 = 3,276,800 f32
    float* u_buf = m_buf + 3276800;             // 16,384 f32
    float* uT_buf = u_buf + BB * DD;            // 16,384 f32
    float* cand_buf = uT_buf + BB * DD;         // 10000*128 = 1,280,000 f32
    int* flag = (int*)(cand_buf + (size_t)NC * DD);  // 1 int (~18.4 MB total)

    k_detect<<<1, 64, 0, stream>>>(queries, flag);
    k_rowsum<SS><<<(BB + 3) / 4, 256, 0, stream>>>(queries, A, u_buf, BB, flag);
    k_rowsum<SS><<<(BB * MM + 3) / 4, 256, 0, stream>>>(stories, A, m_buf, BB * MM, flag);
    k_rowsum<CL><<<(NC + 3) / 4, 256, 0, stream>>>(cands, W, cand_buf, NC, flag);
    for (int h = 0; h < 3; ++h)
        k_hop<<<BB, 256, 0, stream>>>(m_buf, u_buf, Hw, uT_buf);
    k_logits<<<NC / CTILE, 128, 0, stream>>>(uT_buf, cand_buf, out);
}

// Round 4
// 240.709 us; speedup vs baseline: 1.2576x; 1.2576x over previous
//
#include <hip/hip_runtime.h>
#include <hip/hip_bf16.h>
#include <math.h>

#define BB 128
#define MM 200
#define SS 20
#define DD 128
#define NC 10000
#define CL 10
#define CTILE 16

// Detect index width: queries is [128,20] tokens in [0,100000).
// If int64, words at odd positions are the (zero) high halves.
__global__ void k_detect(const int* __restrict__ q, int* __restrict__ flag) {
    int lane = threadIdx.x;
    int zc = 0;
    for (int i = lane; i < 1024; i += 64) zc += (q[2 * i + 1] == 0);
    for (int off = 32; off; off >>= 1) zc += __shfl_down(zc, off);
    if (lane == 0) *flag = (zc >= 512) ? 1 : 0;  // 1 => int64 indices
}

__device__ __forceinline__ unsigned pack_bf16(float a, float b) {
    unsigned ua = __float_as_uint(a), ub = __float_as_uint(b);
    ua += 0x7fff + ((ua >> 16) & 1);  // RNE; inputs finite
    ub += 0x7fff + ((ub >> 16) & 1);
    return (ua >> 16) | (ub & 0xffff0000u);
}
__device__ __forceinline__ float bflo(unsigned v) { return __uint_as_float(v << 16); }
__device__ __forceinline__ float bfhi(unsigned v) { return __uint_as_float(v & 0xffff0000u); }

// Embedding row-sum: half-wave (32 lanes) per row, lane holds float4 (4 dims).
// Tokens preloaded into registers; unconditional gather + multiply-mask so all
// T loads are in flight (row 0 is valid memory; mask zeroes the padding row).
template <int T>
__global__ __launch_bounds__(256) void k_rowsum(const int* __restrict__ idx,
                                                const float* __restrict__ tab,
                                                float* __restrict__ out, int rows,
                                                const int* __restrict__ w64) {
    int row = blockIdx.x * 8 + (threadIdx.x >> 5);
    if (row >= rows) return;
    int l = threadIdx.x & 31;
    int shift = *w64;  // 0: int32 words, 1: int64 (read low word, little-endian)
    int toks[T];
#pragma unroll
    for (int s = 0; s < T; ++s) toks[s] = idx[((size_t)(row * T + s)) << shift];
    float4 acc = make_float4(0.f, 0.f, 0.f, 0.f);
#pragma unroll
    for (int s = 0; s < T; ++s) {
        float4 v = ((const float4*)(tab + (size_t)toks[s] * DD))[l];
        float msk = toks[s] ? 1.f : 0.f;
        acc.x = fmaf(msk, v.x, acc.x);
        acc.y = fmaf(msk, v.y, acc.y);
        acc.z = fmaf(msk, v.z, acc.z);
        acc.w = fmaf(msk, v.w, acc.w);
    }
    ((float4*)(out + (size_t)row * DD))[l] = acc;
}

// All 3 hops fused, one block per batch, m staged ONCE into LDS as bf16x2
// (51.2 KB). dotted -> softmax -> o -> u = tanh(u @ Hw^T + o), iterated 3x
// entirely from LDS. Writes only uT (transposed u) for the logits kernel.
__global__ __launch_bounds__(256) void k_hops(const float* __restrict__ m,
                                              const float* __restrict__ u0,
                                              const float* __restrict__ Hw,
                                              float* __restrict__ uT) {
    __shared__ unsigned m_s[MM][DD / 2];  // packed bf16 pairs, 51.2 KB
    __shared__ float u_s[DD];
    __shared__ float p_s[MM];
    __shared__ float o_s[2][DD];
    __shared__ float red_s;
    int b = blockIdx.x;
    int tid = threadIdx.x;
    int wave = tid >> 6, lane = tid & 63;
    const float2* mb2 = (const float2*)(m + (size_t)b * MM * DD);

    for (int i = tid; i < MM * DD / 2; i += 256) {
        float2 v = mb2[i];
        ((unsigned*)m_s)[i] = pack_bf16(v.x, v.y);
    }
    if (tid < DD) u_s[tid] = u0[b * DD + tid];
    __syncthreads();

    for (int hop = 0; hop < 3; ++hop) {
        // Phase 1: dotted[mm] = m[mm,:] . u  (50 rows/wave, from LDS, shuffle reduce)
        float2 uu = ((const float2*)u_s)[lane];
        for (int i = 0; i < 50; ++i) {
            int mm = wave * 50 + i;
            unsigned pv = m_s[mm][lane];
            float d = bflo(pv) * uu.x + bfhi(pv) * uu.y;
            for (int off = 32; off; off >>= 1) d += __shfl_down(d, off);
            if (lane == 0) p_s[mm] = d;
        }
        __syncthreads();

        // Softmax over 200
        if (wave == 0) {
            float lm = -1e30f;
            for (int i = lane; i < MM; i += 64) lm = fmaxf(lm, p_s[i]);
            for (int off = 32; off; off >>= 1) lm = fmaxf(lm, __shfl_down(lm, off));
            if (lane == 0) red_s = lm;
        }
        __syncthreads();
        float smax = red_s;
        if (tid < MM) p_s[tid] = __expf(p_s[tid] - smax);
        __syncthreads();
        if (wave == 0) {
            float ls = 0.f;
            for (int i = lane; i < MM; i += 64) ls += p_s[i];
            for (int off = 32; off; off >>= 1) ls += __shfl_down(ls, off);
            if (lane == 0) red_s = 1.f / ls;
        }
        __syncthreads();
        float inv = red_s;
        if (tid < MM) p_s[tid] *= inv;
        __syncthreads();

        // Phase 2: o[d] = sum_mm p[mm]*m[mm,d]  (two mm-halves across 256 threads)
        {
            int d = tid & (DD - 1);
            int h = tid >> 7;
            float acc = 0.f;
            for (int mm = h * 100; mm < h * 100 + 100; ++mm) {
                unsigned pv = m_s[mm][d >> 1];
                float mv = (d & 1) ? bfhi(pv) : bflo(pv);
                acc = fmaf(p_s[mm], mv, acc);
            }
            o_s[h][d] = acc;
        }
        __syncthreads();

        // Phase 3: u[d] = tanh( Hw[d,:] . u + o[d] )  (Hw f32 from L1/L2)
        float u_new = 0.f;
        if (tid < DD) {
            const float4* hrow = (const float4*)(Hw + tid * DD);
            float acc = o_s[0][tid] + o_s[1][tid];
            const float4* u4 = (const float4*)u_s;
#pragma unroll 8
            for (int j = 0; j < DD / 4; ++j) {
                float4 hv = hrow[j];
                float4 uv = u4[j];
                acc += hv.x * uv.x + hv.y * uv.y + hv.z * uv.z + hv.w * uv.w;
            }
            u_new = tanhf(acc);
        }
        __syncthreads();  // everyone done reading u_s
        if (tid < DD) u_s[tid] = u_new;
        __syncthreads();
    }

    if (tid < DD) uT[tid * BB + b] = u_s[tid];
}

// logits[b, c] = u[b,:] . cand_sum[c,:]; block = 16 candidates x all 128 batches.
// Thread = one batch row; coalesced uT reads; cand tile broadcast from LDS.
__global__ __launch_bounds__(128) void k_logits(const float* __restrict__ uT,
                                                const float* __restrict__ cs,
                                                float* __restrict__ out) {
    __shared__ float c_s[CTILE][DD];
    int c0 = blockIdx.x * CTILE;
    int tid = threadIdx.x;  // batch index (also dim index for the tile load)
    for (int j = 0; j < CTILE; ++j) c_s[j][tid] = cs[(size_t)(c0 + j) * DD + tid];
    __syncthreads();
    float acc[CTILE];
#pragma unroll
    for (int j = 0; j < CTILE; ++j) acc[j] = 0.f;
    for (int k = 0; k < DD; ++k) {
        float ub = uT[k * BB + tid];
#pragma unroll
        for (int j = 0; j < CTILE; ++j) acc[j] += ub * c_s[j][k];
    }
    // byte addr = 4*(tid*10000 + 16*blk) = 40000*tid + 64*blk -> 16B aligned
    float4* op = (float4*)(out + (size_t)tid * NC + c0);
    op[0] = make_float4(acc[0], acc[1], acc[2], acc[3]);
    op[1] = make_float4(acc[4], acc[5], acc[6], acc[7]);
    op[2] = make_float4(acc[8], acc[9], acc[10], acc[11]);
    op[3] = make_float4(acc[12], acc[13], acc[14], acc[15]);
}

extern "C" void kernel_launch(void* const* d_in, const int* in_sizes, int n_in,
                              void* d_out, int out_size, void* d_ws, size_t ws_size,
                              hipStream_t stream) {
    const int* stories = (const int*)d_in[0];       // [128,200,20] tokens
    const int* queries = (const int*)d_in[1];       // [128,20]
    const int* cands   = (const int*)d_in[2];       // [10000,10]
    const float* A  = (const float*)d_in[3];        // f32 [100000,128]
    const float* W  = (const float*)d_in[4];        // f32 [100000,128]
    const float* Hw = (const float*)d_in[5];        // f32 [128,128]
    float* out = (float*)d_out;                     // f32 [128,10000]

    float* ws = (float*)d_ws;
    float* m_buf = ws;                          // 128*200*128 = 3,276,800 f32
    float* u_buf = m_buf + 3276800;             // 16,384 f32
    float* uT_buf = u_buf + BB * DD;            // 16,384 f32
    float* cand_buf = uT_buf + BB * DD;         // 10000*128 = 1,280,000 f32
    int* flag = (int*)(cand_buf + (size_t)NC * DD);  // 1 int (~18.4 MB total)

    k_detect<<<1, 64, 0, stream>>>(queries, flag);
    k_rowsum<SS><<<(BB + 7) / 8, 256, 0, stream>>>(queries, A, u_buf, BB, flag);
    k_rowsum<SS><<<(BB * MM + 7) / 8, 256, 0, stream>>>(stories, A, m_buf, BB * MM, flag);
    k_rowsum<CL><<<(NC + 7) / 8, 256, 0, stream>>>(cands, W, cand_buf, NC, flag);
    k_hops<<<BB, 256, 0, stream>>>(m_buf, u_buf, Hw, uT_buf);
    k_logits<<<NC / CTILE, 128, 0, stream>>>(uT_buf, cand_buf, out);
}

// Round 5
// 197.475 us; speedup vs baseline: 1.5330x; 1.2189x over previous
//
#include <hip/hip_runtime.h>
#include <hip/hip_bf16.h>
#include <math.h>

#define BB 128
#define MM 200
#define SS 20
#define DD 128
#define NC 10000
#define CL 10
#define CTILE 40

// Detect index width: queries is [128,20] tokens in [0,100000).
// If int64, words at odd positions are the (zero) high halves.
__global__ void k_detect(const int* __restrict__ q, int* __restrict__ flag) {
    int lane = threadIdx.x;
    int zc = 0;
    for (int i = lane; i < 1024; i += 64) zc += (q[2 * i + 1] == 0);
    for (int off = 32; off; off >>= 1) zc += __shfl_down(zc, off);
    if (lane == 0) *flag = (zc >= 512) ? 1 : 0;  // 1 => int64 indices
}

__device__ __forceinline__ unsigned pack_bf16(float a, float b) {
    unsigned ua = __float_as_uint(a), ub = __float_as_uint(b);
    ua += 0x7fff + ((ua >> 16) & 1);  // RNE; inputs finite
    ub += 0x7fff + ((ub >> 16) & 1);
    return (ua >> 16) | (ub & 0xffff0000u);
}
__device__ __forceinline__ float bflo(unsigned v) { return __uint_as_float(v << 16); }
__device__ __forceinline__ float bfhi(unsigned v) { return __uint_as_float(v & 0xffff0000u); }

// One dispatch, 256 blocks x 512 threads.
// Blocks 0..127   : batch b. Gather u0 + story rows (bf16-packed into LDS),
//                   then 3 fused hops entirely from LDS; write uT column.
// Blocks 128..255 : candidate row-sum gather (independent work -> runs on the
//                   otherwise-idle half of the chip, concurrently).
__global__ __launch_bounds__(512) void k_fused(const int* __restrict__ stories,
                                               const int* __restrict__ queries,
                                               const int* __restrict__ cands,
                                               const float* __restrict__ A,
                                               const float* __restrict__ W,
                                               const float* __restrict__ Hw,
                                               float* __restrict__ uT,
                                               float* __restrict__ cand_buf,
                                               const int* __restrict__ flag) {
    __shared__ unsigned m_s[MM][DD / 2];  // packed bf16 pairs, 51.2 KB
    __shared__ float u_s[DD];
    __shared__ float p_s[MM];
    __shared__ float o_part[8][DD];       // 4 KB
    __shared__ float red_s;

    int b = blockIdx.x;
    int tid = threadIdx.x;
    int shift = *flag;  // 0: int32 indices, 1: int64 (read low word, LE)

    if (b < BB) {
        // ---- Stage: gather 200 story rows -> LDS (16 row-groups x 32 lanes,
        //      lane = float4 of dims; 20 unrolled gathers in flight) ----
        int g = tid >> 5, l = tid & 31;
        for (int r = 0; r < 13; ++r) {
            int mm = g + (r << 4);
            if (mm < MM) {
                int toks[SS];
#pragma unroll
                for (int s = 0; s < SS; ++s)
                    toks[s] = stories[((size_t)((b * MM + mm) * SS + s)) << shift];
                float4 acc = make_float4(0.f, 0.f, 0.f, 0.f);
#pragma unroll
                for (int s = 0; s < SS; ++s) {
                    float4 v = ((const float4*)(A + (size_t)toks[s] * DD))[l];
                    float msk = toks[s] ? 1.f : 0.f;  // row 0 = padding
                    acc.x = fmaf(msk, v.x, acc.x);
                    acc.y = fmaf(msk, v.y, acc.y);
                    acc.z = fmaf(msk, v.z, acc.z);
                    acc.w = fmaf(msk, v.w, acc.w);
                }
                m_s[mm][2 * l] = pack_bf16(acc.x, acc.y);
                m_s[mm][2 * l + 1] = pack_bf16(acc.z, acc.w);
            }
        }
        // ---- u0[d] = sum_s A[q[b,s]][d]  (coalesced across threads 0..127) ----
        if (tid < DD) {
            float acc = 0.f;
#pragma unroll
            for (int s = 0; s < SS; ++s) {
                int tok = queries[((size_t)(b * SS + s)) << shift];
                float v = A[(size_t)tok * DD + tid];
                acc += tok ? v : 0.f;
            }
            u_s[tid] = acc;
        }
        __syncthreads();

        for (int hop = 0; hop < 3; ++hop) {
            // Phase 1: p[t] = m[t,:] . u  — one thread per row, rotated LDS
            // access (bank = (t+li)%32 -> conflict-free), no cross-lane ops.
            if (tid < MM) {
                const float2* u2 = (const float2*)u_s;
                float acc = 0.f;
#pragma unroll 8
                for (int li = 0; li < 64; ++li) {
                    int j = (tid + li) & 63;
                    unsigned pv = m_s[tid][j];
                    float2 uv = u2[j];
                    acc += bflo(pv) * uv.x + bfhi(pv) * uv.y;
                }
                p_s[tid] = acc;
            }
            __syncthreads();
            // Softmax over 200 (wave 0; 1/sum deferred to phase 3)
            if (tid < 64) {
                float v0 = p_s[tid], v1 = p_s[tid + 64], v2 = p_s[tid + 128];
                float v3 = (tid < 8) ? p_s[tid + 192] : -1e30f;
                float mx = fmaxf(fmaxf(v0, v1), fmaxf(v2, v3));
                for (int off = 32; off; off >>= 1) mx = fmaxf(mx, __shfl_down(mx, off));
                mx = __shfl(mx, 0);
                float e0 = __expf(v0 - mx), e1 = __expf(v1 - mx), e2 = __expf(v2 - mx);
                float e3 = (tid < 8) ? __expf(v3 - mx) : 0.f;
                float sm = e0 + e1 + e2 + e3;
                for (int off = 32; off; off >>= 1) sm += __shfl_down(sm, off);
                p_s[tid] = e0;
                p_s[tid + 64] = e1;
                p_s[tid + 128] = e2;
                if (tid < 8) p_s[tid + 192] = e3;
                if (tid == 0) red_s = 1.f / __shfl(sm, 0);
            }
            __syncthreads();
            // Phase 2: o[d] = sum_mm e[mm]*m[mm,d], mm split 8 ways (25-chains)
            {
                int c = tid & 63, h = tid >> 6;
                int mm0 = h * 25;
                float ax = 0.f, ay = 0.f;
#pragma unroll 5
                for (int k = 0; k < 25; ++k) {
                    unsigned pv = m_s[mm0 + k][c];
                    float p = p_s[mm0 + k];  // wave-uniform -> broadcast
                    ax = fmaf(p, bflo(pv), ax);
                    ay = fmaf(p, bfhi(pv), ay);
                }
                o_part[h][2 * c] = ax;
                o_part[h][2 * c + 1] = ay;
            }
            __syncthreads();
            // Phase 3: u'[d] = tanh( Hw[d,:] . u + inv * o[d] )
            float u_new = 0.f;
            if (tid < DD) {
                float o = 0.f;
#pragma unroll
                for (int h = 0; h < 8; ++h) o += o_part[h][tid];
                float acc = o * red_s;
                const float4* hrow = (const float4*)(Hw + tid * DD);
                const float4* u4 = (const float4*)u_s;
#pragma unroll 8
                for (int j = 0; j < DD / 4; ++j) {
                    float4 hv = hrow[j];
                    float4 uv = u4[j];
                    acc += hv.x * uv.x + hv.y * uv.y + hv.z * uv.z + hv.w * uv.w;
                }
                u_new = tanhf(acc);
            }
            __syncthreads();
            if (tid < DD) u_s[tid] = u_new;
            __syncthreads();
        }
        if (tid < DD) uT[tid * BB + b] = u_s[tid];
    } else {
        // ---- Candidate row-sums: cand_buf[r,:] = sum_s W[cands[r,s]][:] ----
        int bb = b - BB;
        int g = tid >> 5, l = tid & 31;
        for (int pass = 0; pass < 5; ++pass) {
            int row = (pass << 11) + bb * 16 + g;
            if (row < NC) {
                int toks[CL];
#pragma unroll
                for (int s = 0; s < CL; ++s)
                    toks[s] = cands[((size_t)(row * CL + s)) << shift];
                float4 acc = make_float4(0.f, 0.f, 0.f, 0.f);
#pragma unroll
                for (int s = 0; s < CL; ++s) {
                    float4 v = ((const float4*)(W + (size_t)toks[s] * DD))[l];
                    float msk = toks[s] ? 1.f : 0.f;
                    acc.x = fmaf(msk, v.x, acc.x);
                    acc.y = fmaf(msk, v.y, acc.y);
                    acc.z = fmaf(msk, v.z, acc.z);
                    acc.w = fmaf(msk, v.w, acc.w);
                }
                ((float4*)(cand_buf + (size_t)row * DD))[l] = acc;
            }
        }
    }
}

// logits[b, c] = u[b,:] . cand_sum[c,:]; block = 40 candidates x 128 batches.
// Thread = one batch row; coalesced uT reads; cand tile broadcast from LDS.
__global__ __launch_bounds__(128) void k_logits(const float* __restrict__ uT,
                                                const float* __restrict__ cs,
                                                float* __restrict__ out) {
    __shared__ float c_s[CTILE][DD];  // 20.5 KB
    int c0 = blockIdx.x * CTILE;
    int tid = threadIdx.x;  // batch index (also dim index for the tile load)
#pragma unroll
    for (int j = 0; j < CTILE; ++j) c_s[j][tid] = cs[(size_t)(c0 + j) * DD + tid];
    __syncthreads();
    float acc[CTILE];
#pragma unroll
    for (int j = 0; j < CTILE; ++j) acc[j] = 0.f;
#pragma unroll 4
    for (int k = 0; k < DD; ++k) {
        float ub = uT[k * BB + tid];
#pragma unroll
        for (int j = 0; j < CTILE; ++j) acc[j] += ub * c_s[j][k];
    }
    // byte addr = 4*(tid*10000 + 40*blk) = 40000*tid + 160*blk -> 16B aligned
    float4* op = (float4*)(out + (size_t)tid * NC + c0);
#pragma unroll
    for (int j = 0; j < CTILE / 4; ++j)
        op[j] = make_float4(acc[4 * j], acc[4 * j + 1], acc[4 * j + 2], acc[4 * j + 3]);
}

extern "C" void kernel_launch(void* const* d_in, const int* in_sizes, int n_in,
                              void* d_out, int out_size, void* d_ws, size_t ws_size,
                              hipStream_t stream) {
    const int* stories = (const int*)d_in[0];       // [128,200,20] tokens
    const int* queries = (const int*)d_in[1];       // [128,20]
    const int* cands   = (const int*)d_in[2];       // [10000,10]
    const float* A  = (const float*)d_in[3];        // f32 [100000,128]
    const float* W  = (const float*)d_in[4];        // f32 [100000,128]
    const float* Hw = (const float*)d_in[5];        // f32 [128,128]
    float* out = (float*)d_out;                     // f32 [128,10000]

    float* ws = (float*)d_ws;
    float* cand_buf = ws;                            // 10000*128 f32 = 5.12 MB
    float* uT_buf = cand_buf + (size_t)NC * DD;      // 128*128 f32
    int* flag = (int*)(uT_buf + BB * DD);            // 1 int

    k_detect<<<1, 64, 0, stream>>>(queries, flag);
    k_fused<<<256, 512, 0, stream>>>(stories, queries, cands, A, W, Hw,
                                     uT_buf, cand_buf, flag);
    k_logits<<<NC / CTILE, 128, 0, stream>>>(uT_buf, cand_buf, out);
}

// Round 6
// 184.582 us; speedup vs baseline: 1.6401x; 1.0698x over previous
//
#include <hip/hip_runtime.h>
#include <hip/hip_bf16.h>
#include <math.h>

#define BB 128
#define MM 200
#define SS 20
#define DD 128
#define NC 10000
#define CL 10
#define LCT 64  // logits cand-tile

__device__ __forceinline__ unsigned pack_bf16(float a, float b) {
    unsigned ua = __float_as_uint(a), ub = __float_as_uint(b);
    ua += 0x7fff + ((ua >> 16) & 1);  // RNE; inputs finite
    ub += 0x7fff + ((ub >> 16) & 1);
    return (ua >> 16) | (ub & 0xffff0000u);
}
__device__ __forceinline__ float bflo(unsigned v) { return __uint_as_float(v << 16); }
__device__ __forceinline__ float bfhi(unsigned v) { return __uint_as_float(v & 0xffff0000u); }

// Per-block index-width detection: odd 32-bit words of queries are the high
// halves iff indices are int64 (tokens < 2^32 -> all zero). For int32 they are
// real tokens (P(zero) = 1e-5 each). 8 broadcast loads, no extra dispatch.
__device__ __forceinline__ int detect_shift(const int* __restrict__ q) {
    int zc = 0;
#pragma unroll
    for (int i = 0; i < 8; ++i) zc += (q[2 * i + 1] == 0);
    return (zc >= 6) ? 1 : 0;
}

// A-table f32 -> packed bf16 (halves gather bytes for the story/query phase).
// Row 0 is written as zeros (padding_idx) so gathers need no mask.
__global__ __launch_bounds__(512) void k_conv(const float* __restrict__ A,
                                              unsigned* __restrict__ Abf) {
    size_t t = (size_t)blockIdx.x * 512 + threadIdx.x;  // 8 floats per thread
    const float4* in = (const float4*)(A + t * 8);
    float4 a = in[0], b = in[1];
    if (t * 8 < DD) {  // row 0
        a = make_float4(0.f, 0.f, 0.f, 0.f);
        b = make_float4(0.f, 0.f, 0.f, 0.f);
    }
    uint4 o;
    o.x = pack_bf16(a.x, a.y);
    o.y = pack_bf16(a.z, a.w);
    o.z = pack_bf16(b.x, b.y);
    o.w = pack_bf16(b.z, b.w);
    ((uint4*)(Abf + t * 4))[0] = o;
}

// Blocks 0..127: batch b — gather stories from bf16 A-table into LDS, gather
// u0, run 3 fused hops from LDS, write uT column.
// Blocks 128..752: candidate row-sums from f32 W (overlaps with the
// cache-BW-bound story gather on otherwise-idle CUs).
__global__ __launch_bounds__(512) void k_main(const int* __restrict__ stories,
                                              const int* __restrict__ queries,
                                              const int* __restrict__ cands,
                                              const unsigned* __restrict__ Abf,
                                              const float* __restrict__ W,
                                              const float* __restrict__ Hw,
                                              float* __restrict__ uT,
                                              float* __restrict__ cand_buf) {
    __shared__ unsigned m_s[MM][DD / 2];  // packed bf16 pairs, 51.2 KB
    __shared__ float u_s[DD];
    __shared__ float p_s[MM];
    __shared__ float o_part[8][DD];
    __shared__ float red_s;

    int bid = blockIdx.x;
    int tid = threadIdx.x;
    int shift = detect_shift(queries);

    if (bid < BB) {
        int b = bid;
        // ---- Story gather: 32 groups x 16 lanes; lane = uint4 (8 dims) of a
        //      bf16 row; 20 gathers in flight; no mask (row 0 pre-zeroed). ----
        int g = tid >> 4, l = tid & 15;
#pragma unroll
        for (int r = 0; r < 7; ++r) {
            int mm = g + (r << 5);
            if (mm < MM) {
                int toks[SS];
#pragma unroll
                for (int s = 0; s < SS; ++s)
                    toks[s] = stories[((size_t)((b * MM + mm) * SS + s)) << shift];
                float a[8] = {0.f, 0.f, 0.f, 0.f, 0.f, 0.f, 0.f, 0.f};
#pragma unroll
                for (int s = 0; s < SS; ++s) {
                    uint4 v = ((const uint4*)(Abf + (size_t)toks[s] * (DD / 2)))[l];
                    a[0] += bflo(v.x); a[1] += bfhi(v.x);
                    a[2] += bflo(v.y); a[3] += bfhi(v.y);
                    a[4] += bflo(v.z); a[5] += bfhi(v.z);
                    a[6] += bflo(v.w); a[7] += bfhi(v.w);
                }
                uint4 o;
                o.x = pack_bf16(a[0], a[1]);
                o.y = pack_bf16(a[2], a[3]);
                o.z = pack_bf16(a[4], a[5]);
                o.w = pack_bf16(a[6], a[7]);
                *(uint4*)&m_s[mm][4 * l] = o;
            }
        }
        // ---- u0[d] = sum_s Abf[q[b,s]][d] ----
        if (tid < DD) {
            int d = tid;
            float acc = 0.f;
#pragma unroll
            for (int s = 0; s < SS; ++s) {
                int tok = queries[((size_t)(b * SS + s)) << shift];
                unsigned pv = Abf[(size_t)tok * (DD / 2) + (d >> 1)];
                acc += (d & 1) ? bfhi(pv) : bflo(pv);
            }
            u_s[d] = acc;
        }
        __syncthreads();

        for (int hop = 0; hop < 3; ++hop) {
            // Phase 1: p[t] = m[t,:] . u — thread per row, rotated (conflict-free)
            if (tid < MM) {
                const float2* u2 = (const float2*)u_s;
                float acc = 0.f;
#pragma unroll 8
                for (int li = 0; li < 64; ++li) {
                    int j = (tid + li) & 63;
                    unsigned pv = m_s[tid][j];
                    float2 uv = u2[j];
                    acc += bflo(pv) * uv.x + bfhi(pv) * uv.y;
                }
                p_s[tid] = acc;
            }
            __syncthreads();
            // Softmax over 200 (wave 0; 1/sum deferred to phase 3)
            if (tid < 64) {
                float v0 = p_s[tid], v1 = p_s[tid + 64], v2 = p_s[tid + 128];
                float v3 = (tid < 8) ? p_s[tid + 192] : -1e30f;
                float mx = fmaxf(fmaxf(v0, v1), fmaxf(v2, v3));
                for (int off = 32; off; off >>= 1) mx = fmaxf(mx, __shfl_down(mx, off));
                mx = __shfl(mx, 0);
                float e0 = __expf(v0 - mx), e1 = __expf(v1 - mx), e2 = __expf(v2 - mx);
                float e3 = (tid < 8) ? __expf(v3 - mx) : 0.f;
                float sm = e0 + e1 + e2 + e3;
                for (int off = 32; off; off >>= 1) sm += __shfl_down(sm, off);
                p_s[tid] = e0;
                p_s[tid + 64] = e1;
                p_s[tid + 128] = e2;
                if (tid < 8) p_s[tid + 192] = e3;
                if (tid == 0) red_s = 1.f / __shfl(sm, 0);
            }
            __syncthreads();
            // Phase 2: o[d] = sum_mm e[mm]*m[mm,d], mm split 8 ways
            {
                int c = tid & 63, h = tid >> 6;
                int mm0 = h * 25;
                float ax = 0.f, ay = 0.f;
#pragma unroll 5
                for (int k = 0; k < 25; ++k) {
                    unsigned pv = m_s[mm0 + k][c];
                    float p = p_s[mm0 + k];
                    ax = fmaf(p, bflo(pv), ax);
                    ay = fmaf(p, bfhi(pv), ay);
                }
                o_part[h][2 * c] = ax;
                o_part[h][2 * c + 1] = ay;
            }
            __syncthreads();
            // Phase 3: u'[d] = tanh( Hw[d,:] . u + inv * o[d] )
            float u_new = 0.f;
            if (tid < DD) {
                float o = 0.f;
#pragma unroll
                for (int h = 0; h < 8; ++h) o += o_part[h][tid];
                float acc = o * red_s;
                const float4* hrow = (const float4*)(Hw + tid * DD);
                const float4* u4 = (const float4*)u_s;
#pragma unroll 8
                for (int j = 0; j < DD / 4; ++j) {
                    float4 hv = hrow[j];
                    float4 uv = u4[j];
                    acc += hv.x * uv.x + hv.y * uv.y + hv.z * uv.z + hv.w * uv.w;
                }
                u_new = tanhf(acc);
            }
            __syncthreads();
            if (tid < DD) u_s[tid] = u_new;
            __syncthreads();
        }
        if (tid < DD) uT[tid * BB + bid] = u_s[tid];
    } else {
        // ---- Candidate row-sums from f32 W (masked; W row 0 not zeroed) ----
        int g = tid >> 5, l = tid & 31;
        int row = (bid - BB) * 16 + g;
        int toks[CL];
#pragma unroll
        for (int s = 0; s < CL; ++s)
            toks[s] = cands[((size_t)(row * CL + s)) << shift];
        float4 acc = make_float4(0.f, 0.f, 0.f, 0.f);
#pragma unroll
        for (int s = 0; s < CL; ++s) {
            float4 v = ((const float4*)(W + (size_t)toks[s] * DD))[l];
            float msk = toks[s] ? 1.f : 0.f;
            acc.x = fmaf(msk, v.x, acc.x);
            acc.y = fmaf(msk, v.y, acc.y);
            acc.z = fmaf(msk, v.z, acc.z);
            acc.w = fmaf(msk, v.w, acc.w);
        }
        ((float4*)(cand_buf + (size_t)row * DD))[l] = acc;
    }
}

// logits[b,c] = u[b,:] . cand_sum[c,:]. Block = 128 batches x 64 cands,
// 256 threads; thread = 4-batch x 8-cand register tile. Cand tile transposed
// to k-major in LDS (pad 68) so the inner loop is 2 b128 LDS + 1 float4
// global per 4 k's per thread.
__global__ __launch_bounds__(256) void k_logits(const float* __restrict__ uT,
                                                const float* __restrict__ cs,
                                                float* __restrict__ out) {
    __shared__ float c_s[DD][LCT + 4];  // [k][c], 34.8 KB
    int c0 = blockIdx.x * LCT;
    int tid = threadIdx.x;
    {
        int c = tid >> 2, l = tid & 3;  // c 0..63, l = k-quarter
        int row = c0 + c;
        if (row >= NC) row = NC - 1;
        const float4* rp = (const float4*)(cs + (size_t)row * DD);
#pragma unroll
        for (int i = 0; i < 8; ++i) {
            int k = (l << 5) + (i << 2);
            float4 v = rp[(l << 3) + i];
            c_s[k][c] = v.x;
            c_s[k + 1][c] = v.y;
            c_s[k + 2][c] = v.z;
            c_s[k + 3][c] = v.w;
        }
    }
    __syncthreads();
    int tx = tid & 31, ty = tid >> 5;  // tx: 4 batches, ty: 8 cands
    const float* cb = &c_s[0][ty << 3];
    const float4* up = (const float4*)(uT + (tx << 2));
    float acc[4][8];
#pragma unroll
    for (int i = 0; i < 4; ++i)
#pragma unroll
        for (int j = 0; j < 8; ++j) acc[i][j] = 0.f;
#pragma unroll 4
    for (int k = 0; k < DD; ++k) {
        float4 uv = up[k * (BB / 4)];
        float4 ca = *(const float4*)(cb + k * (LCT + 4));
        float4 cc = *(const float4*)(cb + k * (LCT + 4) + 4);
        float uu[4] = {uv.x, uv.y, uv.z, uv.w};
        float cv[8] = {ca.x, ca.y, ca.z, ca.w, cc.x, cc.y, cc.z, cc.w};
#pragma unroll
        for (int i = 0; i < 4; ++i)
#pragma unroll
            for (int j = 0; j < 8; ++j) acc[i][j] = fmaf(uu[i], cv[j], acc[i][j]);
    }
    if (c0 + (ty << 3) < NC) {  // NC % 8 == 0 -> whole 8-chunk valid
#pragma unroll
        for (int i = 0; i < 4; ++i) {
            float* orow = out + (size_t)((tx << 2) + i) * NC + c0 + (ty << 3);
            ((float4*)orow)[0] = make_float4(acc[i][0], acc[i][1], acc[i][2], acc[i][3]);
            ((float4*)orow)[1] = make_float4(acc[i][4], acc[i][5], acc[i][6], acc[i][7]);
        }
    }
}

extern "C" void kernel_launch(void* const* d_in, const int* in_sizes, int n_in,
                              void* d_out, int out_size, void* d_ws, size_t ws_size,
                              hipStream_t stream) {
    const int* stories = (const int*)d_in[0];       // [128,200,20] tokens
    const int* queries = (const int*)d_in[1];       // [128,20]
    const int* cands   = (const int*)d_in[2];       // [10000,10]
    const float* A  = (const float*)d_in[3];        // f32 [100000,128]
    const float* W  = (const float*)d_in[4];        // f32 [100000,128]
    const float* Hw = (const float*)d_in[5];        // f32 [128,128]
    float* out = (float*)d_out;                     // f32 [128,10000]

    unsigned* Abf = (unsigned*)d_ws;                 // 100000*64 uints = 25.6 MB
    float* cand_buf = (float*)(Abf + 100000 * (DD / 2));  // 5.12 MB
    float* uT_buf = cand_buf + (size_t)NC * DD;      // 64 KB  (total ~30.8 MB)

    k_conv<<<100000 * DD / 8 / 512, 512, 0, stream>>>(A, Abf);
    k_main<<<BB + NC / 16, 512, 0, stream>>>(stories, queries, cands, Abf, W, Hw,
                                             uT_buf, cand_buf);
    k_logits<<<(NC + LCT - 1) / LCT, 256, 0, stream>>>(uT_buf, cand_buf, out);
}